// Round 2
// baseline (246.963 us; speedup 1.0000x reference)
//
#include <hip/hip_runtime.h>
#include <stdint.h>

#define F 128
#define KNB 16
#define TWO_F 256
#define ROWS 64          // rows per block (4 waves x 16 rows)
#define THREADS 256
#define HSTR 133         // f32 stride of LN scratch rows (spread banks)
#define LN_EPS 1e-5f
#define NEG_SLOPE 0.2f

typedef unsigned short u16;
typedef __bf16 bf16x8 __attribute__((ext_vector_type(8)));
typedef float f32x4 __attribute__((ext_vector_type(4)));

union BF8 { bf16x8 v; u16 us[8]; uint4 u4; };

__device__ __forceinline__ float b2f(u16 u) {
    union { float f; uint32_t i; } v; v.i = ((uint32_t)u) << 16; return v.f;
}
__device__ __forceinline__ u16 f2b(float f) {
    union { float f; uint32_t i; } v; v.f = f;
    uint32_t r = (v.i + 0x7FFFu + ((v.i >> 16) & 1u)) >> 16;
    return (u16)r;
}

// 8 f32 -> 8 bf16 per thread
extern "C" __global__ void cast_f32_bf16(const float* __restrict__ src,
                                         u16* __restrict__ dst, int n8) {
    const int i = blockIdx.x * blockDim.x + threadIdx.x;
    if (i >= n8) return;
    const float4* s = (const float4*)src + (size_t)i * 2;
    const float4 a = s[0], b = s[1];
    BF8 o;
    o.us[0] = f2b(a.x); o.us[1] = f2b(a.y); o.us[2] = f2b(a.z); o.us[3] = f2b(a.w);
    o.us[4] = f2b(b.x); o.us[5] = f2b(b.y); o.us[6] = f2b(b.z); o.us[7] = f2b(b.w);
    ((uint4*)dst)[i] = o.u4;
}

// Register-direct front-end (gather + A-fragments straight from global; data and
// per-element summation order bit-identical to the verified LDS-staged kernel),
// verified round-0 LDS epilogue for LayerNorm.
// Lane (ln15, quad) owns A-row = blk*64 + wave*16 + ln15, k-slice quad*8 (+32j).
// C/D layout (verified): col = lane&15, row = quad*4 + reg.
template <int FEAT_BF, int W_BF>
__global__ __launch_bounds__(THREADS, 4)
void gnn_fused(const float* __restrict__ feat_f32, const u16* __restrict__ feat_bf,
               const int* __restrict__ adj,
               const float* __restrict__ W_f32, const u16* __restrict__ W_bf,
               const float* __restrict__ bias, const float* __restrict__ gamma,
               const float* __restrict__ beta,
               float* __restrict__ out, int N)
{
    __shared__ float hb[ROWS * HSTR];   // 34048 B LN scratch

    const int tid  = threadIdx.x;
    const int wave = tid >> 6;
    const int lane = tid & 63;
    const int ln15 = lane & 15;
    const int quad = lane >> 4;
    const int fb   = quad * 8;          // k sub-offset within each 32-chunk
    const int rb   = wave * 16;

    const long rowA  = (long)blockIdx.x * ROWS + rb + ln15;
    const bool rok   = rowA < (long)N;
    const long rsafe = rok ? rowA : 0;

    // ---- neighbor gather-mean: branchy accumulate, identical order to verified kernel ----
    float acc[32];
    #pragma unroll
    for (int t = 0; t < 32; ++t) acc[t] = 0.f;
    int cnt = 0;

    if (rok) {
        const int* adjr = adj + rowA * KNB;   // 64B row, L1-resident after first touch
        for (int k = 0; k < KNB; ++k) {
            const int idx = adjr[k];
            if (idx >= 0 && idx < N) {
                ++cnt;
                if (FEAT_BF) {
                    const u16* nb = feat_bf + (size_t)idx * F + fb;
                    #pragma unroll
                    for (int j = 0; j < 4; ++j) {
                        BF8 u; u.u4 = *(const uint4*)(nb + j * 32);
                        #pragma unroll
                        for (int t = 0; t < 8; ++t) acc[j * 8 + t] += b2f(u.us[t]);
                    }
                } else {
                    const float* nb = feat_f32 + (size_t)idx * F + fb;
                    #pragma unroll
                    for (int j = 0; j < 4; ++j) {
                        const float4 p0 = *(const float4*)(nb + j * 32);
                        const float4 p1 = *(const float4*)(nb + j * 32 + 4);
                        acc[j * 8 + 0] += p0.x; acc[j * 8 + 1] += p0.y;
                        acc[j * 8 + 2] += p0.z; acc[j * 8 + 3] += p0.w;
                        acc[j * 8 + 4] += p1.x; acc[j * 8 + 5] += p1.y;
                        acc[j * 8 + 6] += p1.z; acc[j * 8 + 7] += p1.w;
                    }
                }
            }
        }
    }
    const float scale = 1.f / (float)(cnt > 0 ? cnt : 1);

    // ---- A fragments: own features (ks 0..3) straight from global ----
    bf16x8 afrag[8];
    if (FEAT_BF) {
        const u16* orow = feat_bf + rsafe * F + fb;
        #pragma unroll
        for (int j = 0; j < 4; ++j)
            afrag[j] = *(const bf16x8*)(orow + j * 32);
    } else {
        const float* orow = feat_f32 + rsafe * F + fb;
        #pragma unroll
        for (int j = 0; j < 4; ++j) {
            const float4 p0 = *(const float4*)(orow + j * 32);
            const float4 p1 = *(const float4*)(orow + j * 32 + 4);
            BF8 o;
            o.us[0] = f2b(p0.x); o.us[1] = f2b(p0.y); o.us[2] = f2b(p0.z); o.us[3] = f2b(p0.w);
            o.us[4] = f2b(p1.x); o.us[5] = f2b(p1.y); o.us[6] = f2b(p1.z); o.us[7] = f2b(p1.w);
            afrag[j] = o.v;
        }
    }
    // mean half (ks 4..7)
    #pragma unroll
    for (int j = 0; j < 4; ++j) {
        BF8 o;
        #pragma unroll
        for (int t = 0; t < 8; ++t) o.us[t] = f2b(acc[j * 8 + t] * scale);
        afrag[4 + j] = o.v;
    }

    // ---- GEMM: h[16 x 128] per wave via mfma 16x16x32 bf16, W streamed from L2 ----
    f32x4 accf[8];
    #pragma unroll
    for (int c = 0; c < 8; ++c) accf[c] = (f32x4){0.f, 0.f, 0.f, 0.f};

    #pragma unroll
    for (int ks = 0; ks < 8; ++ks) {
        #pragma unroll
        for (int c = 0; c < 8; ++c) {
            bf16x8 bfrag;
            if (W_BF) {
                bfrag = *(const bf16x8*)(W_bf + (size_t)(c * 16 + ln15) * TWO_F + fb + ks * 32);
            } else {
                const float* wr = W_f32 + (size_t)(c * 16 + ln15) * TWO_F + fb + ks * 32;
                const float4 a = *(const float4*)wr, b = *(const float4*)(wr + 4);
                BF8 o;
                o.us[0] = f2b(a.x); o.us[1] = f2b(a.y); o.us[2] = f2b(a.z); o.us[3] = f2b(a.w);
                o.us[4] = f2b(b.x); o.us[5] = f2b(b.y); o.us[6] = f2b(b.z); o.us[7] = f2b(b.w);
                bfrag = o.v;
            }
            accf[c] = __builtin_amdgcn_mfma_f32_16x16x32_bf16(afrag[ks], bfrag, accf[c], 0, 0, 0);
        }
    }

    // ---- verified epilogue (round-0): h -> LDS, LN with 4 lanes/row ----
    float bval[8];
    #pragma unroll
    for (int c = 0; c < 8; ++c) bval[c] = bias[c * 16 + ln15];

    #pragma unroll
    for (int c = 0; c < 8; ++c) {
        #pragma unroll
        for (int t = 0; t < 4; ++t) {
            const int rr = quad * 4 + t;
            hb[(rb + rr) * HSTR + c * 16 + ln15] = accf[c][t] + bval[c];
        }
    }
    __syncthreads();

    const int er = lane >> 2;                  // row 0..15 within wave slice
    const int eq = lane & 3;                   // 32-col slice
    const float* hr = hb + (rb + er) * HSTR + eq * 32;
    float sum = 0.f, sq = 0.f;
    #pragma unroll
    for (int t = 0; t < 32; ++t) { const float v = hr[t]; sum += v; sq += v * v; }
    sum += __shfl_xor(sum, 1); sq += __shfl_xor(sq, 1);
    sum += __shfl_xor(sum, 2); sq += __shfl_xor(sq, 2);

    const float mu   = sum * (1.f / 128.f);
    const float var  = sq * (1.f / 128.f) - mu * mu;
    const float rsig = rsqrtf(fmaxf(var, 0.f) + LN_EPS);

    const long org = (long)blockIdx.x * ROWS + rb + er;
    if (org < N) {
        const int cb = eq * 32;
        float* orow = out + org * F + cb;
        #pragma unroll
        for (int j = 0; j < 8; ++j) {
            const float4 g  = *(const float4*)(gamma + cb + j * 4);
            const float4 bt = *(const float4*)(beta  + cb + j * 4);
            float4 o;
            o.x = (hr[j * 4 + 0] - mu) * rsig * g.x + bt.x;
            o.y = (hr[j * 4 + 1] - mu) * rsig * g.y + bt.y;
            o.z = (hr[j * 4 + 2] - mu) * rsig * g.z + bt.z;
            o.w = (hr[j * 4 + 3] - mu) * rsig * g.w + bt.w;
            o.x = (o.x >= 0.f) ? o.x : NEG_SLOPE * o.x;
            o.y = (o.y >= 0.f) ? o.y : NEG_SLOPE * o.y;
            o.z = (o.z >= 0.f) ? o.z : NEG_SLOPE * o.z;
            o.w = (o.w >= 0.f) ? o.w : NEG_SLOPE * o.w;
            *(float4*)(orow + j * 4) = o;
        }
    }
}

extern "C" void kernel_launch(void* const* d_in, const int* in_sizes, int n_in,
                              void* d_out, int out_size, void* d_ws, size_t ws_size,
                              hipStream_t stream) {
    const float* feat  = (const float*)d_in[0];
    const int*   adj   = (const int*)d_in[1];
    const float* W     = (const float*)d_in[2];
    const float* bias  = (const float*)d_in[3];
    const float* gamma = (const float*)d_in[4];
    const float* beta  = (const float*)d_in[5];
    float* out = (float*)d_out;

    const int N = in_sizes[0] / F;
    const size_t needW = (size_t)TWO_F * F * sizeof(u16);        // 65536 B
    const size_t needF = (size_t)N * F * sizeof(u16);            // ~25.6 MB
    u16* wsW = (u16*)d_ws;
    u16* wsF = (u16*)((char*)d_ws + needW);

    const int mode = (ws_size >= needW + needF) ? 2 : (ws_size >= needW ? 1 : 0);

    if (mode >= 1) {
        const int n8 = TWO_F * F / 8;
        cast_f32_bf16<<<dim3((n8 + 255) / 256), dim3(256), 0, stream>>>(W, wsW, n8);
    }
    if (mode == 2) {
        const int n8 = N * F / 8;   // N*F divisible by 8
        cast_f32_bf16<<<dim3((n8 + 255) / 256), dim3(256), 0, stream>>>(feat, wsF, n8);
    }

    const int blocks = (N + ROWS - 1) / ROWS;
    if (mode == 2) {
        gnn_fused<1, 1><<<dim3(blocks), dim3(THREADS), 0, stream>>>(feat, wsF, adj, W, wsW, bias, gamma, beta, out, N);
    } else if (mode == 1) {
        gnn_fused<0, 1><<<dim3(blocks), dim3(THREADS), 0, stream>>>(feat, wsF, adj, W, wsW, bias, gamma, beta, out, N);
    } else {
        gnn_fused<0, 0><<<dim3(blocks), dim3(THREADS), 0, stream>>>(feat, wsF, adj, W, wsW, bias, gamma, beta, out, N);
    }
}

// Round 4
// 237.830 us; speedup vs baseline: 1.0384x; 1.0384x over previous
//
#include <hip/hip_runtime.h>
#include <stdint.h>

#define F 128
#define KNB 16
#define TWO_F 256
#define ROWS 64          // rows per block (4 waves x 16 rows)
#define THREADS 256
#define HSTR 133         // f32 stride of LN scratch rows (spread banks)
#define LN_EPS 1e-5f
#define NEG_SLOPE 0.2f

typedef unsigned short u16;
typedef __bf16 bf16x8 __attribute__((ext_vector_type(8)));
typedef float f32x4 __attribute__((ext_vector_type(4)));

union BF8 { bf16x8 v; u16 us[8]; uint4 u4; };

__device__ __forceinline__ float b2f(u16 u) {
    union { float f; uint32_t i; } v; v.i = ((uint32_t)u) << 16; return v.f;
}
__device__ __forceinline__ u16 f2b(float f) {
    union { float f; uint32_t i; } v; v.f = f;
    uint32_t r = (v.i + 0x7FFFu + ((v.i >> 16) & 1u)) >> 16;
    return (u16)r;
}

// 8 f32 -> 8 bf16 per thread
extern "C" __global__ void cast_f32_bf16(const float* __restrict__ src,
                                         u16* __restrict__ dst, int n8) {
    const int i = blockIdx.x * blockDim.x + threadIdx.x;
    if (i >= n8) return;
    const float4* s = (const float4*)src + (size_t)i * 2;
    const float4 a = s[0], b = s[1];
    BF8 o;
    o.us[0] = f2b(a.x); o.us[1] = f2b(a.y); o.us[2] = f2b(a.z); o.us[3] = f2b(a.w);
    o.us[4] = f2b(b.x); o.us[5] = f2b(b.y); o.us[6] = f2b(b.z); o.us[7] = f2b(b.w);
    ((uint4*)dst)[i] = o.u4;
}

// Register-direct front-end; adjacency hoisted to registers (no loads on the
// serial k-chain); verified LDS epilogue with wave-local sync only.
// Lane (ln15, quad) owns A-row = blk*64 + wave*16 + ln15, k-slice quad*8 (+32j).
// C/D layout (verified): col = lane&15, row = quad*4 + reg.
template <int FEAT_BF, int W_BF>
__global__ __launch_bounds__(THREADS, 4)
void gnn_fused(const float* __restrict__ feat_f32, const u16* __restrict__ feat_bf,
               const int* __restrict__ adj,
               const float* __restrict__ W_f32, const u16* __restrict__ W_bf,
               const float* __restrict__ bias, const float* __restrict__ gamma,
               const float* __restrict__ beta,
               float* __restrict__ out, int N)
{
    __shared__ float hb[ROWS * HSTR];   // 34048 B LN scratch (per-wave regions)

    const int tid  = threadIdx.x;
    const int wave = tid >> 6;
    const int lane = tid & 63;
    const int ln15 = lane & 15;
    const int quad = lane >> 4;
    const int fb   = quad * 8;          // k sub-offset within each 32-chunk
    const int rb   = wave * 16;

    const long rowA  = (long)blockIdx.x * ROWS + rb + ln15;
    const bool rok   = rowA < (long)N;
    const long rsafe = rok ? rowA : 0;

    // ---- adjacency: hoist all 16 ids to registers (4x int4, one 64B line) ----
    int idx[16];
    {
        const int4* ap = (const int4*)(adj + rsafe * KNB);
        const int4 a0 = ap[0], a1 = ap[1], a2 = ap[2], a3 = ap[3];
        idx[0]  = a0.x; idx[1]  = a0.y; idx[2]  = a0.z; idx[3]  = a0.w;
        idx[4]  = a1.x; idx[5]  = a1.y; idx[6]  = a1.z; idx[7]  = a1.w;
        idx[8]  = a2.x; idx[9]  = a2.y; idx[10] = a2.z; idx[11] = a2.w;
        idx[12] = a3.x; idx[13] = a3.y; idx[14] = a3.z; idx[15] = a3.w;
    }

    // ---- own features -> A-frag (ks 0..3): issue these loads early ----
    bf16x8 afrag[8];
    if (FEAT_BF) {
        const u16* orow = feat_bf + rsafe * F + fb;
        #pragma unroll
        for (int j = 0; j < 4; ++j)
            afrag[j] = *(const bf16x8*)(orow + j * 32);
    } else {
        const float* orow = feat_f32 + rsafe * F + fb;
        #pragma unroll
        for (int j = 0; j < 4; ++j) {
            const float4 p0 = *(const float4*)(orow + j * 32);
            const float4 p1 = *(const float4*)(orow + j * 32 + 4);
            BF8 o;
            o.us[0] = f2b(p0.x); o.us[1] = f2b(p0.y); o.us[2] = f2b(p0.z); o.us[3] = f2b(p0.w);
            o.us[4] = f2b(p1.x); o.us[5] = f2b(p1.y); o.us[6] = f2b(p1.z); o.us[7] = f2b(p1.w);
            afrag[j] = o.v;
        }
    }

    // ---- neighbor gather-mean: branchy accumulate (order identical to verified) ----
    float acc[32];
    #pragma unroll
    for (int t = 0; t < 32; ++t) acc[t] = 0.f;
    int cnt = 0;

    if (rok) {
        for (int k = 0; k < KNB; ++k) {
            const int id = idx[k];
            if (id >= 0 && id < N) {
                ++cnt;
                if (FEAT_BF) {
                    const u16* nb = feat_bf + (size_t)id * F + fb;
                    #pragma unroll
                    for (int j = 0; j < 4; ++j) {
                        BF8 u; u.u4 = *(const uint4*)(nb + j * 32);
                        #pragma unroll
                        for (int t = 0; t < 8; ++t) acc[j * 8 + t] += b2f(u.us[t]);
                    }
                } else {
                    const float* nb = feat_f32 + (size_t)id * F + fb;
                    #pragma unroll
                    for (int j = 0; j < 4; ++j) {
                        const float4 p0 = *(const float4*)(nb + j * 32);
                        const float4 p1 = *(const float4*)(nb + j * 32 + 4);
                        acc[j * 8 + 0] += p0.x; acc[j * 8 + 1] += p0.y;
                        acc[j * 8 + 2] += p0.z; acc[j * 8 + 3] += p0.w;
                        acc[j * 8 + 4] += p1.x; acc[j * 8 + 5] += p1.y;
                        acc[j * 8 + 6] += p1.z; acc[j * 8 + 7] += p1.w;
                    }
                }
            }
        }
    }
    const float scale = 1.f / (float)(cnt > 0 ? cnt : 1);

    // mean half (ks 4..7)
    #pragma unroll
    for (int j = 0; j < 4; ++j) {
        BF8 o;
        #pragma unroll
        for (int t = 0; t < 8; ++t) o.us[t] = f2b(acc[j * 8 + t] * scale);
        afrag[4 + j] = o.v;
    }

    // ---- GEMM: h[16 x 128] per wave via mfma 16x16x32 bf16, W streamed from L2 ----
    f32x4 accf[8];
    #pragma unroll
    for (int c = 0; c < 8; ++c) accf[c] = (f32x4){0.f, 0.f, 0.f, 0.f};

    #pragma unroll
    for (int ks = 0; ks < 8; ++ks) {
        #pragma unroll
        for (int c = 0; c < 8; ++c) {
            bf16x8 bfrag;
            if (W_BF) {
                bfrag = *(const bf16x8*)(W_bf + (size_t)(c * 16 + ln15) * TWO_F + fb + ks * 32);
            } else {
                const float* wr = W_f32 + (size_t)(c * 16 + ln15) * TWO_F + fb + ks * 32;
                const float4 a = *(const float4*)wr, b = *(const float4*)(wr + 4);
                BF8 o;
                o.us[0] = f2b(a.x); o.us[1] = f2b(a.y); o.us[2] = f2b(a.z); o.us[3] = f2b(a.w);
                o.us[4] = f2b(b.x); o.us[5] = f2b(b.y); o.us[6] = f2b(b.z); o.us[7] = f2b(b.w);
                bfrag = o.v;
            }
            accf[c] = __builtin_amdgcn_mfma_f32_16x16x32_bf16(afrag[ks], bfrag, accf[c], 0, 0, 0);
        }
    }

    // ---- verified epilogue: h -> per-wave LDS region, LN with 4 lanes/row ----
    float bval[8];
    #pragma unroll
    for (int c = 0; c < 8; ++c) bval[c] = bias[c * 16 + ln15];

    #pragma unroll
    for (int c = 0; c < 8; ++c) {
        #pragma unroll
        for (int t = 0; t < 4; ++t) {
            const int rr = quad * 4 + t;
            hb[(rb + rr) * HSTR + c * 16 + ln15] = accf[c][t] + bval[c];
        }
    }
    // hb region is strictly per-wave: wave-local LDS drain suffices (no block barrier).
    // sched_barrier(0) pins the following ds_reads after the waitcnt (rule #18 defense).
    asm volatile("s_waitcnt lgkmcnt(0)" ::: "memory");
    __builtin_amdgcn_sched_barrier(0);

    const int er = lane >> 2;                  // row 0..15 within wave slice
    const int eq = lane & 3;                   // 32-col slice
    const float* hr = hb + (rb + er) * HSTR + eq * 32;
    float sum = 0.f, sq = 0.f;
    #pragma unroll
    for (int t = 0; t < 32; ++t) { const float v = hr[t]; sum += v; sq += v * v; }
    sum += __shfl_xor(sum, 1); sq += __shfl_xor(sq, 1);
    sum += __shfl_xor(sum, 2); sq += __shfl_xor(sq, 2);

    const float mu   = sum * (1.f / 128.f);
    const float var  = sq * (1.f / 128.f) - mu * mu;
    const float rsig = rsqrtf(fmaxf(var, 0.f) + LN_EPS);

    const long org = (long)blockIdx.x * ROWS + rb + er;
    if (org < N) {
        const int cb = eq * 32;
        float* orow = out + org * F + cb;
        #pragma unroll
        for (int j = 0; j < 8; ++j) {
            const float4 g  = *(const float4*)(gamma + cb + j * 4);
            const float4 bt = *(const float4*)(beta  + cb + j * 4);
            float4 o;
            o.x = (hr[j * 4 + 0] - mu) * rsig * g.x + bt.x;
            o.y = (hr[j * 4 + 1] - mu) * rsig * g.y + bt.y;
            o.z = (hr[j * 4 + 2] - mu) * rsig * g.z + bt.z;
            o.w = (hr[j * 4 + 3] - mu) * rsig * g.w + bt.w;
            o.x = (o.x >= 0.f) ? o.x : NEG_SLOPE * o.x;
            o.y = (o.y >= 0.f) ? o.y : NEG_SLOPE * o.y;
            o.z = (o.z >= 0.f) ? o.z : NEG_SLOPE * o.z;
            o.w = (o.w >= 0.f) ? o.w : NEG_SLOPE * o.w;
            *(float4*)(orow + j * 4) = o;
        }
    }
}

extern "C" void kernel_launch(void* const* d_in, const int* in_sizes, int n_in,
                              void* d_out, int out_size, void* d_ws, size_t ws_size,
                              hipStream_t stream) {
    const float* feat  = (const float*)d_in[0];
    const int*   adj   = (const int*)d_in[1];
    const float* W     = (const float*)d_in[2];
    const float* bias  = (const float*)d_in[3];
    const float* gamma = (const float*)d_in[4];
    const float* beta  = (const float*)d_in[5];
    float* out = (float*)d_out;

    const int N = in_sizes[0] / F;
    const size_t needW = (size_t)TWO_F * F * sizeof(u16);        // 65536 B
    const size_t needF = (size_t)N * F * sizeof(u16);            // ~25.6 MB
    u16* wsW = (u16*)d_ws;
    u16* wsF = (u16*)((char*)d_ws + needW);

    const int mode = (ws_size >= needW + needF) ? 2 : (ws_size >= needW ? 1 : 0);

    if (mode >= 1) {
        const int n8 = TWO_F * F / 8;
        cast_f32_bf16<<<dim3((n8 + 255) / 256), dim3(256), 0, stream>>>(W, wsW, n8);
    }
    if (mode == 2) {
        const int n8 = N * F / 8;   // N*F divisible by 8
        cast_f32_bf16<<<dim3((n8 + 255) / 256), dim3(256), 0, stream>>>(feat, wsF, n8);
    }

    const int blocks = (N + ROWS - 1) / ROWS;
    if (mode == 2) {
        gnn_fused<1, 1><<<dim3(blocks), dim3(THREADS), 0, stream>>>(feat, wsF, adj, W, wsW, bias, gamma, beta, out, N);
    } else if (mode == 1) {
        gnn_fused<0, 1><<<dim3(blocks), dim3(THREADS), 0, stream>>>(feat, wsF, adj, W, wsW, bias, gamma, beta, out, N);
    } else {
        gnn_fused<0, 0><<<dim3(blocks), dim3(THREADS), 0, stream>>>(feat, wsF, adj, W, wsW, bias, gamma, beta, out, N);
    }
}